// Round 4
// baseline (36.977 us; speedup 1.0000x reference)
//
#include <hip/hip_runtime.h>
#include <math.h>

// ChamferLoss: pc_src [B,3,M] f32, pc_dst [B,3,N] f32 -> scalar mean over (B,M)
// of min_n ||src_m - dst_n||.
//
// Identity: min_n d2 = |a|^2 + min_n (|b|^2 - 2 a.b).
// Per-dst float4 (-2bx,-2by,-2bz,|b|^2) staged in LDS -> inner loop is
// 3 FMA + half a v_min3 per pair (3.5 VALU lane-ops/pair, floor ~11.9 us).
//
// R3 -> R4: two dispatches only. minseg: SPT=4/NSEG=64 -> 2048 blocks =
// exactly 8 blocks/CU (8 waves/SIMD, launch_bounds(256,8), no tail round);
// partial minima stored plain (no atomics, no memset — ws needs no init).
// finish: seg-reduce + sqrt + block sum, accumulated via deterministic
// fixed-point u64 atomicAdd; last block (ticket) writes the scalar. The
// ticket/sum cells are zeroed by minseg block 0 (runs before finish in
// stream order).

#define TPB 256

constexpr int NB = 4;
constexpr int NM = 8192;
constexpr int NN = 8192;
constexpr int NSEG = 64;                          // dst segments
constexpr int SEG = NN / NSEG;                    // 128 dst per segment
constexpr int SPT = 4;                            // src points per thread
constexpr int SRC_PER_BLOCK = TPB * SPT;          // 1024
constexpr int NPTS = NB * NM;                     // 32768
constexpr int CHUNKS = NPTS / SRC_PER_BLOCK;      // 32
constexpr int CHUNKS_PER_B = NM / SRC_PER_BLOCK;  // 8
constexpr int NBLK_C = NPTS / TPB;                // 128

// Kernel 1: per (src-chunk, dst-segment) block. Build the segment's dst4 in
// LDS, running min of (b^2 - 2 a.b) over 4 src points/thread, store partial.
__global__ __launch_bounds__(TPB, 8) void minseg_kernel(const float* __restrict__ src,
                                                        const float* __restrict__ dst,
                                                        float* __restrict__ part,
                                                        unsigned long long* __restrict__ sumfix,
                                                        unsigned* __restrict__ ticket) {
    __shared__ float4 sdst[SEG];                  // 2 KB

    int chunk = blockIdx.x % CHUNKS;
    int seg   = blockIdx.x / CHUNKS;
    int b  = chunk / CHUNKS_PER_B;
    int t  = threadIdx.x;

    if (blockIdx.x == 0 && t == 0) { *sumfix = 0ULL; *ticket = 0u; }

    if (t < SEG) {
        int n = seg * SEG + t;
        const float* p = dst + (size_t)b * 3 * NN;
        float x = p[n], y = p[NN + n], z = p[2 * NN + n];
        sdst[t] = make_float4(-2.0f * x, -2.0f * y, -2.0f * z,
                              fmaf(x, x, fmaf(y, y, z * z)));
    }

    int m0 = (chunk % CHUNKS_PER_B) * SRC_PER_BLOCK + t;
    const float* sp = src + (size_t)b * 3 * NM;

    float ax[SPT], ay[SPT], az[SPT], mn[SPT];
#pragma unroll
    for (int k = 0; k < SPT; ++k) {
        int m = m0 + k * TPB;
        ax[k] = sp[m];
        ay[k] = sp[NM + m];
        az[k] = sp[2 * NM + m];
        mn[k] = 3.4e38f;
    }
    __syncthreads();

#pragma unroll 4
    for (int j = 0; j < SEG; j += 2) {
        float4 d0 = sdst[j];                      // uniform -> LDS broadcast
        float4 d1 = sdst[j + 1];
#pragma unroll
        for (int k = 0; k < SPT; ++k) {
            float t0 = fmaf(az[k], d0.z, d0.w);
            t0 = fmaf(ay[k], d0.y, t0);
            t0 = fmaf(ax[k], d0.x, t0);
            float t1 = fmaf(az[k], d1.z, d1.w);
            t1 = fmaf(ay[k], d1.y, t1);
            t1 = fmaf(ax[k], d1.x, t1);
            mn[k] = fminf(fminf(mn[k], t0), t1);  // -> v_min3_f32
        }
    }

#pragma unroll
    for (int k = 0; k < SPT; ++k) {
        int gm = b * NM + m0 + k * TPB;
        part[(size_t)seg * NPTS + gm] = mn[k];    // coalesced store
    }
}

// Kernel 2: per src point min over segments, d = sqrt(max(a^2+v,0)),
// block tree-sum, fixed-point device accumulate; last block writes out.
__global__ __launch_bounds__(TPB) void finish_kernel(const float* __restrict__ src,
                                                     const float* __restrict__ part,
                                                     unsigned long long* __restrict__ sumfix,
                                                     unsigned* __restrict__ ticket,
                                                     float* __restrict__ out) {
    int gm = blockIdx.x * TPB + threadIdx.x;
    int b = gm / NM, m = gm % NM;

    float v = fminf(part[gm], part[NPTS + gm]);
#pragma unroll 8
    for (int s = 2; s < NSEG; s += 2)
        v = fminf(fminf(v, part[(size_t)s * NPTS + gm]),
                  part[(size_t)(s + 1) * NPTS + gm]);   // -> v_min3_f32

    const float* sp = src + (size_t)b * 3 * NM;
    float x = sp[m], y = sp[NM + m], z = sp[2 * NM + m];
    float a2 = fmaf(x, x, fmaf(y, y, z * z));
    float d = sqrtf(fmaxf(a2 + v, 0.0f));

    for (int off = 32; off > 0; off >>= 1) d += __shfl_down(d, off);
    __shared__ float wsum[4];
    int lane = threadIdx.x & 63, w = threadIdx.x >> 6;
    if (lane == 0) wsum[w] = d;
    __syncthreads();

    if (threadIdx.x == 0) {
        float bs = (wsum[0] + wsum[1]) + (wsum[2] + wsum[3]);
        // Fixed-point (32.32) accumulate: integer adds are associative ->
        // deterministic regardless of block order.
        unsigned long long inc = (unsigned long long)((double)bs * 4294967296.0);
        atomicAdd(sumfix, inc);
        __threadfence();                          // sum-add before ticket-add
        unsigned tk = atomicAdd(ticket, 1u);
        if (tk == NBLK_C - 1) {
            unsigned long long tot = atomicAdd(sumfix, 0ULL);  // coherent read
            out[0] = (float)((double)tot * (1.0 / 4294967296.0) * (1.0 / NPTS));
        }
    }
}

extern "C" void kernel_launch(void* const* d_in, const int* in_sizes, int n_in,
                              void* d_out, int out_size, void* d_ws, size_t ws_size,
                              hipStream_t stream) {
    const float* src = (const float*)d_in[0];   // [B,3,M]
    const float* dst = (const float*)d_in[1];   // [B,3,N]
    float* out = (float*)d_out;

    char* ws = (char*)d_ws;
    float* part = (float*)ws;                                        // 8 MB
    unsigned long long* sumfix =
        (unsigned long long*)(ws + (size_t)NSEG * NPTS * 4);         // 8 B
    unsigned* ticket = (unsigned*)(ws + (size_t)NSEG * NPTS * 4 + 8);// 4 B

    minseg_kernel<<<CHUNKS * NSEG, TPB, 0, stream>>>(src, dst, part, sumfix, ticket);
    finish_kernel<<<NBLK_C, TPB, 0, stream>>>(src, part, sumfix, ticket, out);
}